// Round 3
// baseline (1626.551 us; speedup 1.0000x reference)
//
#include <hip/hip_runtime.h>
#include <math.h>
#include <stdint.h>

// ---------------- constants ----------------
#define BATCH 2
#define NIN   1024
#define NSEQ  2048
#define DIMC  512
#define NH    8
#define DHD   64
#define MLM   17
#define LBLK  125
#define SEQ   2117      // 1 + 2116
#define NPAD  2125      // SEQ + 8
#define PAD0  8
#define HS    46
#define NPIX  2116      // 46*46
#define RA    4250      // BATCH*NPAD rows of the stacked activation matrices
#define WRAP  68        // SEQ-1-NSEQ wrap rows
#define AWSZ  ((size_t)BATCH*NH*NPAD*NPAD)   // 72,250,000

// weight-pack offsets in halves: [fc1 | qkv0 | qkv1 | out0 | out1]
#define WOFF_FC1  0
#define WOFF_QKV0 524288
#define WOFF_QKV1 1310720
#define WOFF_OUT0 2097152
#define WOFF_OUT1 2359296
#define WTOT      2621440

typedef _Float16 half8 __attribute__((ext_vector_type(8)));
typedef float    floatx4 __attribute__((ext_vector_type(4)));

// write one fp32 value as hi/lo _Float16 pair in granule-major layout [k/8][row][8], row-stride RA
__device__ __forceinline__ void store_hl(_Float16* __restrict__ xh, _Float16* __restrict__ xl,
                                         int c, int ra, float v)
{
    _Float16 hv = (_Float16)v;
    size_t o = ((size_t)(c >> 3) * RA + ra) * 8 + (c & 7);
    xh[o] = hv;
    xl[o] = (_Float16)(v - (float)hv);
}

// ---------------- conversion: feats fp32 [4096][1024] -> granule-major hi/lo halves; also writes cls rows of h
__global__ void convA_kernel(const float* __restrict__ X, _Float16* __restrict__ hi,
                             _Float16* __restrict__ lo, const float* __restrict__ cls,
                             float* __restrict__ h)
{
    const int R = 4096, K = NIN, GK = K >> 3;
    if (blockIdx.x == 0) {
        int b = threadIdx.x >> 7, c4 = threadIdx.x & 127;
        ((float4*)h)[((size_t)(b * SEQ)) * (DIMC/4) + c4] = ((const float4*)cls)[c4];
    }
    size_t idx = (size_t)blockIdx.x * 256 + threadIdx.x;
    if (idx >= (size_t)R * GK) return;
    int r = (int)(idx % R); int gk = (int)(idx / R);
    const float* s = X + (size_t)r * K + gk * 8;
    half8 hv, lv;
    #pragma unroll
    for (int j = 0; j < 8; ++j) {
        float x = s[j];
        _Float16 hh = (_Float16)x;
        hv[j] = hh;
        lv[j] = (_Float16)(x - (float)hh);
    }
    *(half8*)(hi + idx * 8) = hv;   // offset == ((size_t)gk*R + r)*8
    *(half8*)(lo + idx * 8) = lv;
}

// ---------------- batched weight conversion: 5 matrices fp32 [K][N] -> B^T granule-major hi/lo ----------------
__global__ void convW_kernel(const float* __restrict__ s0, const float* __restrict__ s1,
                             const float* __restrict__ s2, const float* __restrict__ s3,
                             const float* __restrict__ s4,
                             _Float16* __restrict__ Wh, _Float16* __restrict__ Wl)
{
    int job = blockIdx.y;
    const float* S; int N, K; size_t doff;
    if      (job == 0) { S = s0; N = 512;  K = 1024; doff = WOFF_FC1;  }
    else if (job == 1) { S = s1; N = 1536; K = 512;  doff = WOFF_QKV0; }
    else if (job == 2) { S = s2; N = 1536; K = 512;  doff = WOFF_QKV1; }
    else if (job == 3) { S = s3; N = 512;  K = 512;  doff = WOFF_OUT0; }
    else               { S = s4; N = 512;  K = 512;  doff = WOFF_OUT1; }
    int GK = K >> 3;
    size_t idx = (size_t)blockIdx.x * 256 + threadIdx.x;
    if (idx >= (size_t)N * GK) return;
    int n = (int)(idx % N); int gk = (int)(idx / N);
    const float* s = S + (size_t)(gk * 8) * N + n;
    half8 hv, lv;
    #pragma unroll
    for (int j = 0; j < 8; ++j) {
        float x = s[(size_t)j * N];
        _Float16 hh = (_Float16)x;
        hv[j] = hh;
        lv[j] = (_Float16)(x - (float)hh);
    }
    *(half8*)(Wh + doff + idx * 8) = hv;
    *(half8*)(Wl + doff + idx * 8) = lv;
}

// ---------------- MFMA GEMM, f16x3 split, 2-phase double-buffered staging ----------------
// A,B granule-major hi/lo halves: A[k/8][m][8], B^T[k/8][n][8]. 128x128 tile, 4 waves, K-step 32.
// mode 1: qkv split -> q(x0.125)/k/v head-major.   mode 2: fc1 -> h rows (+bias,+relu, wrap dup).
// mode 3: proj -> h += (+bias), rows PAD0.. only.
__global__ __launch_bounds__(256) void gemm_mfma(
    const _Float16* __restrict__ Ah, const _Float16* __restrict__ Al,
    const _Float16* __restrict__ Bh, const _Float16* __restrict__ Bl,
    const float* __restrict__ bias, float* __restrict__ C,
    int Mn, int Nn, int Kn, int mode,
    float* __restrict__ qp, float* __restrict__ kp, float* __restrict__ vp)
{
    __shared__ _Float16 sA[2][2][4][128][8];   // [buf][hi/lo][granule][row][8] = 32 KB
    __shared__ _Float16 sB[2][2][4][128][8];   // 32 KB
    const int tid = threadIdx.x;
    const int wv = tid >> 6, ln = tid & 63;
    const int m0 = blockIdx.y * 128, n0 = blockIdx.x * 128;
    const int wm = (wv >> 1) * 64, wn = (wv & 1) * 64;
    const int g = ln >> 4, rr = ln & 15;

    floatx4 acc[4][4];
    #pragma unroll
    for (int m = 0; m < 4; ++m)
        #pragma unroll
        for (int n = 0; n < 4; ++n)
            acc[m][n] = (floatx4){0.f, 0.f, 0.f, 0.f};

    auto STAGE = [&](int bf, int gk0) {
        #pragma unroll
        for (int q2 = 0; q2 < 8; ++q2) {
            int c = wv + q2 * 4;
            int arr = c >> 3, gg = (c >> 1) & 3, hf = c & 1;
            const _Float16* base = (arr == 0) ? Ah : (arr == 1) ? Al : (arr == 2) ? Bh : Bl;
            int Rdim = (arr < 2) ? Mn : Nn;
            int rg = ((arr < 2) ? m0 : n0) + hf * 64 + ln;
            if (arr < 2 && rg >= Mn) rg = Mn - 1;   // clamp tail rows (stores are guarded)
            const _Float16* src = base + ((size_t)(gk0 + gg) * Rdim + rg) * 8;
            _Float16* dst = (arr == 0) ? &sA[bf][0][gg][hf * 64][0] :
                            (arr == 1) ? &sA[bf][1][gg][hf * 64][0] :
                            (arr == 2) ? &sB[bf][0][gg][hf * 64][0] :
                                         &sB[bf][1][gg][hf * 64][0];
            __builtin_amdgcn_global_load_lds(
                (__attribute__((address_space(1))) void*)(uintptr_t)src,
                (__attribute__((address_space(3))) void*)dst, 16, 0, 0);
        }
    };

    const int nt = Kn >> 5;
    STAGE(0, 0);
    __syncthreads();
    for (int t = 0; t < nt; ++t) {
        const int cur = t & 1;
        if (t + 1 < nt) STAGE(cur ^ 1, (t + 1) * 4);   // prefetch issued BEFORE compute
        half8 a_h[4], a_l[4], b_h[4], b_l[4];
        #pragma unroll
        for (int m = 0; m < 4; ++m) {
            a_h[m] = *(const half8*)&sA[cur][0][g][wm + m * 16 + rr][0];
            a_l[m] = *(const half8*)&sA[cur][1][g][wm + m * 16 + rr][0];
        }
        #pragma unroll
        for (int n = 0; n < 4; ++n) {
            b_h[n] = *(const half8*)&sB[cur][0][g][wn + n * 16 + rr][0];
            b_l[n] = *(const half8*)&sB[cur][1][g][wn + n * 16 + rr][0];
        }
        #pragma unroll
        for (int m = 0; m < 4; ++m)
            #pragma unroll
            for (int n = 0; n < 4; ++n) {
                acc[m][n] = __builtin_amdgcn_mfma_f32_16x16x32_f16(a_h[m], b_h[n], acc[m][n], 0, 0, 0);
                acc[m][n] = __builtin_amdgcn_mfma_f32_16x16x32_f16(a_l[m], b_h[n], acc[m][n], 0, 0, 0);
                acc[m][n] = __builtin_amdgcn_mfma_f32_16x16x32_f16(a_h[m], b_l[n], acc[m][n], 0, 0, 0);
            }
        __syncthreads();   // one barrier per K-step: drains prefetch + protects both buffers
    }

    // epilogue: C/D layout col = lane&15, row = (lane>>4)*4 + r
    const int rq = ln >> 4;
    if (mode == 2) {
        // fc1 -> h directly: row r=b*2048+n -> h row b*SEQ+1+n, wrap dup for n<WRAP; +bias, relu
        #pragma unroll
        for (int n = 0; n < 4; ++n) {
            int col = n0 + wn + n * 16 + rr;
            float bv = bias[col];
            #pragma unroll
            for (int m = 0; m < 4; ++m) {
                #pragma unroll
                for (int r = 0; r < 4; ++r) {
                    int row = m0 + wm + m * 16 + rq * 4 + r;   // < 4096 by grid
                    float vv = fmaxf(acc[m][n][r] + bv, 0.f);
                    int b = row >> 11, nn = row & 2047;
                    C[((size_t)(b * SEQ + 1 + nn)) * DIMC + col] = vv;
                    if (nn < WRAP)
                        C[((size_t)(b * SEQ + 1 + NSEQ + nn)) * DIMC + col] = vv;
                }
            }
        }
    } else if (mode == 3) {
        // proj -> h += : row r=b*NPAD+i -> h row b*SEQ+(i-PAD0) for i>=PAD0; +bias
        #pragma unroll
        for (int n = 0; n < 4; ++n) {
            int col = n0 + wn + n * 16 + rr;
            float bv = bias[col];
            #pragma unroll
            for (int m = 0; m < 4; ++m) {
                #pragma unroll
                for (int r = 0; r < 4; ++r) {
                    int row = m0 + wm + m * 16 + rq * 4 + r;
                    if (row < Mn) {
                        int b = (row >= NPAD) ? 1 : 0;
                        int i = row - b * NPAD;
                        if (i >= PAD0) {
                            size_t o = ((size_t)(b * SEQ + i - PAD0)) * DIMC + col;
                            C[o] += acc[m][n][r] + bv;
                        }
                    }
                }
            }
        }
    } else {
        // qkv split: col in [0,1536): sect=col>>9 (q/k/v), head=(col>>6)&7, d=col&63
        #pragma unroll
        for (int n = 0; n < 4; ++n) {
            int col = n0 + wn + n * 16 + rr;
            int sect = col >> 9, hh = (col >> 6) & 7, dd = col & 63;
            float* dstb = (sect == 0) ? qp : (sect == 1) ? kp : vp;
            float sc = (sect == 0) ? 0.125f : 1.f;
            #pragma unroll
            for (int m = 0; m < 4; ++m) {
                #pragma unroll
                for (int r = 0; r < 4; ++r) {
                    int row = m0 + wm + m * 16 + rq * 4 + r;
                    if (row < Mn) {
                        int b = (row >= NPAD) ? 1 : 0;
                        int i = row - b * NPAD;
                        dstb[(((size_t)(b * NH + hh)) * NPAD + i) * DHD + dd] = acc[m][n][r] * sc;
                    }
                }
            }
        }
    }
}

// ---------------- LayerNorm rows of h -> granule-major hi/lo halves (rows 0..7 zero) ----------------
__global__ void ln_pad_kernel(const float* __restrict__ h, const float* __restrict__ g,
                              const float* __restrict__ bta,
                              _Float16* __restrict__ xh, _Float16* __restrict__ xl)
{
    int r = blockIdx.x; int b = blockIdx.y; int t = threadIdx.x; // block 256
    int ra = b*NPAD + r;
    if (r < PAD0) {
        store_hl(xh, xl, t, ra, 0.f);
        store_hl(xh, xl, t + 256, ra, 0.f);
        return;
    }
    const float* x = &h[((size_t)(b*SEQ + r-PAD0))*DIMC];
    __shared__ float ws[4];
    int wid = t >> 6, ln = t & 63;
    float x0 = x[t], x1 = x[t+256];
    float s = x0 + x1;
    #pragma unroll
    for (int m = 1; m < 64; m <<= 1) s += __shfl_xor(s, m, 64);
    if (ln == 0) ws[wid] = s;
    __syncthreads();
    float mu = (ws[0]+ws[1]+ws[2]+ws[3]) * (1.f/512.f);
    float d0 = x0-mu, d1 = x1-mu;
    float vv = d0*d0 + d1*d1;
    #pragma unroll
    for (int m = 1; m < 64; m <<= 1) vv += __shfl_xor(vv, m, 64);
    __syncthreads();
    if (ln == 0) ws[wid] = vv;
    __syncthreads();
    float rstd = 1.0f / sqrtf((ws[0]+ws[1]+ws[2]+ws[3])*(1.f/512.f) + 1e-5f);
    store_hl(xh, xl, t,       ra, d0*rstd*g[t]     + bta[t]);
    store_hl(xh, xl, t + 256, ra, d1*rstd*g[t+256] + bta[t+256]);
}

// ---------------- landmarks: mean over 125-blocks (4-wave split) ----------------
__global__ void landmark_kernel(const float* __restrict__ q, const float* __restrict__ k,
                                float* __restrict__ ql, float* __restrict__ kl)
{
    int m = blockIdx.x, h = blockIdx.y, b = blockIdx.z;
    int t = threadIdx.x; // 256
    int wv = t >> 6, d = t & 63;
    int bh = b*NH + h;
    size_t base = ((size_t)bh*NPAD + m*LBLK)*DHD + d;
    float sq = 0.f, sk = 0.f;
    for (int r = wv; r < LBLK; r += 4) {
        sq += q[base + (size_t)r*DHD];
        sk += k[base + (size_t)r*DHD];
    }
    __shared__ float rq[4][64], rk[4][64];
    rq[wv][d] = sq; rk[wv][d] = sk;
    __syncthreads();
    if (wv == 0) {
        size_t o = ((size_t)bh*MLM + m)*DHD + d;
        ql[o] = (rq[0][d]+rq[1][d]+rq[2][d]+rq[3][d]) / 125.f;
        kl[o] = (rk[0][d]+rk[1][d]+rk[2][d]+rk[3][d]) / 125.f;
    }
}

// ---------------- a3 = softmax(ql @ k^T) rows + fused a3v = a3row @ v ----------------
__global__ void a3_kernel(const float* __restrict__ ql, const float* __restrict__ k,
                          const float* __restrict__ v, float* __restrict__ a3,
                          float* __restrict__ a3v)
{
    int m = blockIdx.x, h = blockIdx.y, b = blockIdx.z;
    int bh = b*NH + h; int tid = threadIdx.x; // 256
    __shared__ alignas(16) float qlrow[64];
    __shared__ float buf[NPAD];
    __shared__ float red[256];
    __shared__ float pvred[4][64];
    if (tid < 64) qlrow[tid] = ql[((size_t)bh*MLM+m)*DHD + tid];
    __syncthreads();
    for (int j = tid; j < NPAD; j += 256) {
        const float4* kr4 = (const float4*)&k[((size_t)bh*NPAD + j)*DHD];
        const float4* q4 = (const float4*)qlrow;
        float acc = 0.f;
        #pragma unroll
        for (int d4=0; d4<16; ++d4) {
            float4 kk = kr4[d4], qq = q4[d4];
            acc += qq.x*kk.x + qq.y*kk.y + qq.z*kk.z + qq.w*kk.w;
        }
        buf[j] = acc;
    }
    __syncthreads();
    float mx = -1e30f;
    for (int j = tid; j < NPAD; j += 256) mx = fmaxf(mx, buf[j]);
    red[tid] = mx; __syncthreads();
    for (int s=128;s>0;s>>=1){ if(tid<s) red[tid]=fmaxf(red[tid],red[tid+s]); __syncthreads(); }
    mx = red[0]; __syncthreads();
    float sm = 0.f;
    for (int j = tid; j < NPAD; j += 256) sm += expf(buf[j]-mx);
    red[tid] = sm; __syncthreads();
    for (int s=128;s>0;s>>=1){ if(tid<s) red[tid]+=red[tid+s]; __syncthreads(); }
    sm = red[0];
    float inv = 1.f/sm;
    float* a3r = &a3[((size_t)bh*MLM+m)*NPAD];
    for (int j = tid; j < NPAD; j += 256) {
        float pv = expf(buf[j]-mx)*inv;
        buf[j] = pv;
        a3r[j] = pv;
    }
    __syncthreads();
    // fused a3v: 4-wave partial dot over j
    int wv = tid >> 6, ln = tid & 63;
    int c0 = wv * 532, c1 = c0 + 532; if (c1 > NPAD) c1 = NPAD;
    float acc = 0.f;
    const float* vb = &v[(size_t)bh*NPAD*DHD + ln];
    for (int j = c0; j < c1; ++j) acc += buf[j] * vb[(size_t)j*DHD];
    pvred[wv][ln] = acc;
    __syncthreads();
    if (wv == 0)
        a3v[((size_t)bh*MLM+m)*DHD + ln] = pvred[0][ln]+pvred[1][ln]+pvred[2][ln]+pvred[3][ln];
}

// ---------------- pinv: computes a2 (all bh, in LDS) + global scale + 6 iterations ----------------
__global__ void pinv_kernel(const float* __restrict__ ql, const float* __restrict__ kl,
                            float* __restrict__ a2i)
{
    int bh = blockIdx.x; int t = threadIdx.x; // 320
    __shared__ float a2all[16*289];   // 18.5 KB
    __shared__ float x[289], z[289], xz[289], w1[289], w2[289];
    __shared__ float red[320], red2[320];
    // phase 1: all 16 a2 dot matrices
    for (int e = t; e < 16*289; e += 320) {
        int g2 = e / 289, cell = e % 289, i2 = cell / MLM, j2 = cell % MLM;
        const float4* qr = (const float4*)&ql[((size_t)g2*MLM + i2)*DHD];
        const float4* kr = (const float4*)&kl[((size_t)g2*MLM + j2)*DHD];
        float acc = 0.f;
        #pragma unroll
        for (int d4 = 0; d4 < 16; ++d4) {
            float4 a = qr[d4], bb = kr[d4];
            acc += a.x*bb.x + a.y*bb.y + a.z*bb.z + a.w*bb.w;
        }
        a2all[e] = acc;
    }
    __syncthreads();
    // phase 2: softmax each of the 272 rows
    if (t < 16*MLM) {
        float* row = &a2all[(t/MLM)*289 + (t%MLM)*MLM];
        float mx = row[0];
        for (int u = 1; u < MLM; ++u) mx = fmaxf(mx, row[u]);
        float sm = 0.f;
        for (int u = 0; u < MLM; ++u) { float e2 = expf(row[u]-mx); row[u] = e2; sm += e2; }
        float inv = 1.f/sm;
        for (int u = 0; u < MLM; ++u) row[u] *= inv;
    }
    __syncthreads();
    // phase 3: global max abs row-sum / col-sum
    float rs = -1e30f, cs = -1e30f;
    if (t < 16*MLM) {
        int g2 = t/MLM, i2 = t%MLM;
        const float* M = &a2all[g2*289];
        float r = 0.f, c = 0.f;
        for (int j = 0; j < MLM; ++j) { r += fabsf(M[i2*MLM+j]); c += fabsf(M[j*MLM+i2]); }
        rs = r; cs = c;
    }
    red[t] = rs; red2[t] = cs; __syncthreads();
    for (int s=256;s>0;s>>=1){
        if (t<s && t+s<320){ red[t]=fmaxf(red[t],red[t+s]); red2[t]=fmaxf(red2[t],red2[t+s]); }
        __syncthreads();
    }
    float scal = 1.f/(red[0]*red2[0]);
    // phase 4: iterate on own bh
    int i = t/MLM, j = t%MLM;
    bool act = t < MLM*MLM;
    if (act) x[t] = a2all[bh*289 + t];
    __syncthreads();
    if (act) z[t] = x[j*MLM+i] * scal;
    __syncthreads();
    for (int it=0; it<6; ++it) {
        if (act){ float a=0.f; for(int k2=0;k2<MLM;++k2) a += x[i*MLM+k2]*z[k2*MLM+j]; xz[t]=a; }
        __syncthreads();
        if (act){ w1[t] = (i==j?7.f:0.f) - xz[t]; }
        __syncthreads();
        if (act){ float a=0.f; for(int k2=0;k2<MLM;++k2) a += xz[i*MLM+k2]*w1[k2*MLM+j]; w2[t]=a; }
        __syncthreads();
        if (act){ w1[t] = (i==j?15.f:0.f) - w2[t]; }
        __syncthreads();
        if (act){ float a=0.f; for(int k2=0;k2<MLM;++k2) a += xz[i*MLM+k2]*w1[k2*MLM+j]; w2[t]=a; }
        __syncthreads();
        if (act){ w1[t] = (i==j?13.f:0.f) - w2[t]; }
        __syncthreads();
        if (act){ float a=0.f; for(int k2=0;k2<MLM;++k2) a += z[i*MLM+k2]*w1[k2*MLM+j]; w2[t]=0.25f*a; }
        __syncthreads();
        if (act) z[t] = w2[t];
        __syncthreads();
    }
    if (act) a2i[(size_t)bh*MLM*MLM + t] = z[t];
}

// ---------------- fused: a1 softmax + left row + headout (left@a3v + res conv) ----------------
__global__ void a1l_ho_kernel(const float* __restrict__ q, const float* __restrict__ kl,
                              const float* __restrict__ a2i, const float* __restrict__ a3v,
                              const float* __restrict__ v, const float* __restrict__ res_w,
                              float* __restrict__ left,
                              _Float16* __restrict__ hh, _Float16* __restrict__ hl)
{
    int i = blockIdx.x, h = blockIdx.y, b = blockIdx.z;
    int bh = b*NH + h; int lane = threadIdx.x; // 64
    __shared__ alignas(16) float qrow[64];
    __shared__ float dots[MLM];
    __shared__ float arow[MLM];
    __shared__ float lrow[MLM];
    __shared__ float rw[33];
    qrow[lane] = q[((size_t)bh*NPAD + i)*DHD + lane];
    if (lane >= 17 && lane < 50) rw[lane-17] = res_w[h*33 + (lane-17)];
    __syncthreads();
    if (lane < MLM) {
        const float4* kr4 = (const float4*)&kl[((size_t)bh*MLM + lane)*DHD];
        const float4* q4 = (const float4*)qrow;
        float acc = 0.f;
        #pragma unroll
        for (int d4=0; d4<16; ++d4) {
            float4 a = q4[d4], bb = kr4[d4];
            acc += a.x*bb.x + a.y*bb.y + a.z*bb.z + a.w*bb.w;
        }
        dots[lane] = acc;
    }
    __syncthreads();
    if (lane < MLM) {
        float mx = -1e30f;
        for (int u=0;u<MLM;++u) mx = fmaxf(mx, dots[u]);
        float s = 0.f;
        for (int u=0;u<MLM;++u) s += expf(dots[u]-mx);
        arow[lane] = expf(dots[lane]-mx)/s;
    }
    __syncthreads();
    if (lane < MLM) {
        const float* zi = &a2i[(size_t)bh*MLM*MLM];
        float acc = 0.f;
        for (int k2=0;k2<MLM;++k2) acc += arow[k2]*zi[k2*MLM + lane];
        lrow[lane] = acc;
        left[((size_t)bh*NPAD + i)*MLM + lane] = acc;
    }
    __syncthreads();
    // headout part (all 64 lanes)
    float acc = 0.f;
    const float* a3vb = &a3v[(size_t)bh*MLM*DHD];
    #pragma unroll
    for (int m2=0;m2<MLM;++m2) acc += lrow[m2]*a3vb[m2*DHD + lane];
    for (int s=0;s<33;++s) {
        int ii = i + s - 16;
        if (ii >= 0 && ii < NPAD) acc += rw[s]*v[((size_t)bh*NPAD+ii)*DHD + lane];
    }
    store_hl(hh, hl, h*DHD + lane, b*NPAD + i, acc);
}

// ---------------- attn map write: aw = left @ a3, tiled (64 i x 512 j per block) ----------------
__global__ __launch_bounds__(256) void attn_out_kernel(const float* __restrict__ left,
                                                       const float* __restrict__ a3,
                                                       float* __restrict__ aw)
{
    int bh = blockIdx.z; int i0 = blockIdx.y*64; int j0 = blockIdx.x*512;
    int t = threadIdx.x;
    __shared__ float lrows[64][20];   // padded leading dim (80B, 16B-aligned rows)
    for (int u = t; u < 64*MLM; u += 256) {
        int ii = u / MLM, kk = u % MLM;
        int gi = i0 + ii;
        lrows[ii][kk] = (gi < NPAD) ? left[((size_t)bh*NPAD + gi)*MLM + kk] : 0.f;
    }
    __syncthreads();
    int j1 = j0 + t, j2 = j0 + 256 + t;
    float c1[MLM], c2[MLM];
    #pragma unroll
    for (int kk = 0; kk < MLM; ++kk) {
        c1[kk] = (j1 < NPAD) ? a3[((size_t)bh*MLM + kk)*NPAD + j1] : 0.f;
        c2[kk] = (j2 < NPAD) ? a3[((size_t)bh*MLM + kk)*NPAD + j2] : 0.f;
    }
    int imax = NPAD - i0; if (imax > 64) imax = 64;
    for (int ii = 0; ii < imax; ++ii) {
        float lv[17];
        *(float4*)&lv[0]  = *(const float4*)&lrows[ii][0];
        *(float4*)&lv[4]  = *(const float4*)&lrows[ii][4];
        *(float4*)&lv[8]  = *(const float4*)&lrows[ii][8];
        *(float4*)&lv[12] = *(const float4*)&lrows[ii][12];
        lv[16] = lrows[ii][16];
        float s1 = 0.f, s2 = 0.f;
        #pragma unroll
        for (int kk = 0; kk < MLM; ++kk) { s1 += lv[kk]*c1[kk]; s2 += lv[kk]*c2[kk]; }
        size_t ob = ((size_t)bh*NPAD + (i0+ii))*NPAD;
        if (j1 < NPAD) aw[ob + j1] = s1;
        if (j2 < NPAD) aw[ob + j2] = s2;
    }
}

// ---------------- PPEG: LDS-tiled transpose h(tokens x chan) -> im[b][c][p] ----------------
__global__ void transpose_h2im(const float* __restrict__ h, float* __restrict__ im)
{
    __shared__ float tile[32][33];
    int p0 = blockIdx.x*32, c0 = blockIdx.y*32, b = blockIdx.z;
    int tx = threadIdx.x & 31, ty = threadIdx.x >> 5; // 32x8
    #pragma unroll
    for (int i=0;i<32;i+=8) {
        int p = p0 + ty + i;
        if (p < NPIX) tile[ty+i][tx] = h[((size_t)(b*SEQ) + 1 + p)*DIMC + c0 + tx];
    }
    __syncthreads();
    #pragma unroll
    for (int i=0;i<32;i+=8) {
        int c = c0 + ty + i, p = p0 + tx;
        if (p < NPIX) im[((size_t)(b*DIMC) + c)*NPIX + p] = tile[tx][ty+i];
    }
}

// ---------------- PPEG: 7/5/3 depthwise convs + identity, channel-major in/out ----------------
__global__ void ppeg_conv_kernel(const float* __restrict__ im,
                                 const float* __restrict__ w7, const float* __restrict__ b7,
                                 const float* __restrict__ w5, const float* __restrict__ b5,
                                 const float* __restrict__ w3, const float* __restrict__ b3,
                                 float* __restrict__ im2)
{
    int c = blockIdx.x; int b = blockIdx.y; int t = threadIdx.x; // 256
    __shared__ float img[NPIX];
    __shared__ float wf[49+25+9];
    const float* src = &im[((size_t)(b*DIMC+c))*NPIX];
    for (int p=t; p<NPIX; p+=256) img[p] = src[p];
    if (t < 49) wf[t] = w7[c*49+t];
    else if (t >= 64 && t < 64+25) wf[49 + (t-64)] = w5[c*25 + (t-64)];
    else if (t >= 96 && t < 96+9)  wf[74 + (t-96)] = w3[c*9 + (t-96)];
    __syncthreads();
    float bias = b7[c] + b5[c] + b3[c];
    for (int p=t; p<NPIX; p+=256) {
        int y = p/HS, x = p%HS;
        float acc = img[p] + bias;
        for (int dy=-3; dy<=3; ++dy){ int yy=y+dy; if (yy<0||yy>=HS) continue;
            for (int dx=-3; dx<=3; ++dx){ int xx=x+dx; if (xx<0||xx>=HS) continue;
                acc += wf[(dy+3)*7+(dx+3)]*img[yy*HS+xx]; } }
        for (int dy=-2; dy<=2; ++dy){ int yy=y+dy; if (yy<0||yy>=HS) continue;
            for (int dx=-2; dx<=2; ++dx){ int xx=x+dx; if (xx<0||xx>=HS) continue;
                acc += wf[49+(dy+2)*5+(dx+2)]*img[yy*HS+xx]; } }
        for (int dy=-1; dy<=1; ++dy){ int yy=y+dy; if (yy<0||yy>=HS) continue;
            for (int dx=-1; dx<=1; ++dx){ int xx=x+dx; if (xx<0||xx>=HS) continue;
                acc += wf[74+(dy+1)*3+(dx+1)]*img[yy*HS+xx]; } }
        im2[((size_t)(b*DIMC)+c)*NPIX + p] = acc;
    }
}

// ---------------- PPEG: LDS-tiled transpose im2[b][c][p] -> h rows ----------------
__global__ void transpose_im2h(const float* __restrict__ im2, float* __restrict__ h)
{
    __shared__ float tile[32][33];
    int p0 = blockIdx.x*32, c0 = blockIdx.y*32, b = blockIdx.z;
    int tx = threadIdx.x & 31, ty = threadIdx.x >> 5; // 32x8
    #pragma unroll
    for (int i=0;i<32;i+=8) {
        int c = c0 + ty + i, p = p0 + tx;
        if (p < NPIX) tile[ty+i][tx] = im2[((size_t)(b*DIMC) + c)*NPIX + p];
    }
    __syncthreads();
    #pragma unroll
    for (int i=0;i<32;i+=8) {
        int p = p0 + ty + i;
        if (p < NPIX) h[((size_t)(b*SEQ) + 1 + p)*DIMC + c0 + tx] = tile[tx][ty+i];
    }
}

// ---------------- final: LN(cls row) @ fc2 + bias -> logits ----------------
__global__ void final_kernel(const float* __restrict__ h, const float* __restrict__ g,
                             const float* __restrict__ bta, const float* __restrict__ fc2w,
                             const float* __restrict__ fc2b, float* __restrict__ out)
{
    int b = blockIdx.x; int t = threadIdx.x; // 512
    __shared__ float red[512];
    const float* x = &h[(size_t)b*SEQ*DIMC];
    float xv = x[t];
    red[t] = xv; __syncthreads();
    for (int s=256;s>0;s>>=1){ if(t<s) red[t]+=red[t+s]; __syncthreads(); }
    float mu = red[0]/512.f; __syncthreads();
    float d = xv - mu;
    red[t] = d*d; __syncthreads();
    for (int s=256;s>0;s>>=1){ if(t<s) red[t]+=red[t+s]; __syncthreads(); }
    float var = red[0]/512.f; __syncthreads();
    float hn = d * (1.f/sqrtf(var+1e-5f)) * g[t] + bta[t];
    for (int c=0;c<2;++c) {
        red[t] = hn * fc2w[t*2+c]; __syncthreads();
        for (int s=256;s>0;s>>=1){ if(t<s) red[t]+=red[t+s]; __syncthreads(); }
        if (t==0) out[b*2+c] = red[0] + fc2b[c];
        __syncthreads();
    }
}

// ================= host =================
extern "C" void kernel_launch(void* const* d_in, const int* in_sizes, int n_in,
                              void* d_out, int out_size, void* d_ws, size_t ws_size,
                              hipStream_t stream)
{
    (void)in_sizes; (void)n_in; (void)out_size; (void)ws_size;
    const float* feats = (const float*)d_in[0];
    const float* fc1_w = (const float*)d_in[1];
    const float* fc1_b = (const float*)d_in[2];
    const float* cls   = (const float*)d_in[3];
    const float* ln_g[2]  = {(const float*)d_in[4],  (const float*)d_in[10]};
    const float* ln_b[2]  = {(const float*)d_in[5],  (const float*)d_in[11]};
    const float* qkv_w[2] = {(const float*)d_in[6],  (const float*)d_in[12]};
    const float* out_w[2] = {(const float*)d_in[7],  (const float*)d_in[13]};
    const float* out_b[2] = {(const float*)d_in[8],  (const float*)d_in[14]};
    const float* res_w[2] = {(const float*)d_in[9],  (const float*)d_in[15]};
    const float* w7 = (const float*)d_in[16]; const float* b7 = (const float*)d_in[17];
    const float* w5 = (const float*)d_in[18]; const float* b5 = (const float*)d_in[19];
    const float* w3 = (const float*)d_in[20]; const float* b3 = (const float*)d_in[21];
    const float* ng = (const float*)d_in[22]; const float* nb = (const float*)d_in[23];
    const float* fc2w = (const float*)d_in[24]; const float* fc2b = (const float*)d_in[25];

    float* ws = (float*)d_ws;
    size_t off = 0;
    float* h    = ws + off; off += (size_t)BATCH*SEQ*DIMC;      // 2,167,808
    float* im   = ws + off; off += (size_t)BATCH*DIMC*NPIX;     // 2,166,784
    float* im2  = ws + off; off += (size_t)BATCH*DIMC*NPIX;     // 2,166,784
    float* q    = ws + off; off += (size_t)BATCH*NH*NPAD*DHD;
    float* k    = ws + off; off += (size_t)BATCH*NH*NPAD*DHD;
    float* v    = ws + off; off += (size_t)BATCH*NH*NPAD*DHD;
    float* ql   = ws + off; off += (size_t)BATCH*NH*MLM*DHD;
    float* kl   = ws + off; off += (size_t)BATCH*NH*MLM*DHD;
    float* a2i  = ws + off; off += (size_t)BATCH*NH*MLM*MLM + 16;
    float* a3   = ws + off; off += (size_t)BATCH*NH*MLM*NPAD;
    float* left = ws + off; off += (size_t)BATCH*NH*NPAD*MLM;
    float* a3v  = ws + off; off += (size_t)BATCH*NH*MLM*DHD;
    _Float16* XAh = (_Float16*)(ws + off); off += 2097152;   // 4,194,304 halves (fc1 A / layer A)
    _Float16* XAl = (_Float16*)(ws + off); off += 2097152;
    _Float16* Wh  = (_Float16*)(ws + off); off += (WTOT+1)/2;
    _Float16* Wl  = (_Float16*)(ws + off); off += (WTOT+1)/2;

    float* outp = (float*)d_out;

    // pre: conversions (convA also writes cls rows of h), fc1 GEMM writes h directly
    convA_kernel<<<2048, 256, 0, stream>>>(feats, XAh, XAl, cls, h);
    convW_kernel<<<dim3(384, 5), 256, 0, stream>>>(
        fc1_w, qkv_w[0], qkv_w[1], out_w[0], out_w[1], Wh, Wl);
    gemm_mfma<<<dim3(DIMC/128, 4096/128), 256, 0, stream>>>(
        XAh, XAl, Wh + WOFF_FC1, Wl + WOFF_FC1, fc1_b, h, 4096, DIMC, NIN, 2,
        nullptr, nullptr, nullptr);

    const size_t qoffs[2] = {WOFF_QKV0, WOFF_QKV1};
    const size_t ooffs[2] = {WOFF_OUT0, WOFF_OUT1};
    for (int L = 0; L < 2; ++L) {
        float* aw = outp + 4 + (size_t)L*AWSZ;
        ln_pad_kernel<<<dim3(NPAD, BATCH), 256, 0, stream>>>(h, ln_g[L], ln_b[L], XAh, XAl);
        gemm_mfma<<<dim3(1536/128, (RA+127)/128), 256, 0, stream>>>(
            XAh, XAl, Wh + qoffs[L], Wl + qoffs[L], nullptr, nullptr, RA, 1536, DIMC, 1, q, k, v);
        landmark_kernel<<<dim3(MLM, NH, BATCH), 256, 0, stream>>>(q, k, ql, kl);
        pinv_kernel<<<BATCH*NH, 320, 0, stream>>>(ql, kl, a2i);
        a3_kernel<<<dim3(MLM, NH, BATCH), 256, 0, stream>>>(ql, k, v, a3, a3v);
        a1l_ho_kernel<<<dim3(NPAD, NH, BATCH), 64, 0, stream>>>(
            q, kl, a2i, a3v, v, res_w[L], left, XAh, XAl);
        attn_out_kernel<<<dim3((NPAD+511)/512, (NPAD+63)/64, BATCH*NH), 256, 0, stream>>>(left, a3, aw);
        gemm_mfma<<<dim3(DIMC/128, (RA+127)/128), 256, 0, stream>>>(
            XAh, XAl, Wh + ooffs[L], Wl + ooffs[L], out_b[L], h, RA, DIMC, DIMC, 3,
            nullptr, nullptr, nullptr);
        if (L == 0) {
            transpose_h2im<<<dim3((NPIX+31)/32, DIMC/32, BATCH), 256, 0, stream>>>(h, im);
            ppeg_conv_kernel<<<dim3(DIMC, BATCH), 256, 0, stream>>>(im, w7, b7, w5, b5, w3, b3, im2);
            transpose_im2h<<<dim3((NPIX+31)/32, DIMC/32, BATCH), 256, 0, stream>>>(im2, h);
        }
    }
    final_kernel<<<BATCH, 512, 0, stream>>>(h, ng, nb, fc2w, fc2b, outp);
}